// Round 2
// baseline (504.901 us; speedup 1.0000x reference)
//
#include <hip/hip_runtime.h>

#define NDIM 512   // D_IN == D_OUT == 512

typedef __bf16 bf16x8 __attribute__((ext_vector_type(8)));
typedef float  f32x4  __attribute__((ext_vector_type(4)));

__device__ inline ushort f2bf(float f) {           // fp32 -> bf16 RNE
    uint b = __float_as_uint(f);
    return (ushort)((b + 0x7fffu + ((b >> 16) & 1u)) >> 16);
}
__device__ inline float bflo(uint u) { return __uint_as_float(u << 16); }
__device__ inline float bfhi(uint u) { return __uint_as_float(u & 0xffff0000u); }
__device__ inline uint packbf(float lo, float hi) {
    return ((uint)f2bf(hi) << 16) | (uint)f2bf(lo);
}

// async global->LDS, 16B per lane; lds base must be wave-uniform (dest = base + lane*16)
__device__ inline void gload16(const ushort* g, ushort* l) {
    __builtin_amdgcn_global_load_lds(
        (const __attribute__((address_space(1))) uint*)g,
        (__attribute__((address_space(3))) uint*)l, 16, 0, 0);
}

// ---------------- fp32 -> bf16 bulk convert (float4 -> ushort4) ----------------
__global__ __launch_bounds__(256) void f2bf_kernel(const float* __restrict__ in,
                                                   ushort* __restrict__ out, int n4) {
    int i = blockIdx.x * 256 + threadIdx.x;
    if (i >= n4) return;
    float4 v = ((const float4*)in)[i];
    ushort4 o;
    o.x = f2bf(v.x); o.y = f2bf(v.y); o.z = f2bf(v.z); o.w = f2bf(v.w);
    ((ushort4*)out)[i] = o;
}

// ---------------- histograms: deg_row[row]++, cnt_col[col]++ ----------------
__global__ __launch_bounds__(256) void hist_kernel(const int* __restrict__ ei,
                                                   int* __restrict__ deg_row,
                                                   int* __restrict__ cnt_col, int E) {
    int e = blockIdx.x * 256 + threadIdx.x;
    if (e < E) {
        atomicAdd(&deg_row[ei[e]], 1);
        atomicAdd(&cnt_col[ei[E + e]], 1);
    }
}

// ---------------- dis[i] = deg>0 ? rsqrt(deg) : 0 ----------------
__global__ __launch_bounds__(256) void rsqrt_kernel(const int* __restrict__ deg,
                                                    float* __restrict__ dis, int n) {
    int i = blockIdx.x * 256 + threadIdx.x;
    if (i < n) {
        int d = deg[i];
        dis[i] = (d > 0) ? rsqrtf((float)d) : 0.0f;
    }
}

// ------- single-block exclusive scan over PADDED counts pc=(cnt+7)&~7 -------
// base[i] = fill_cnt[i] = exclusive prefix; base[n] = padded total.
// (buckets padded to x8 so agg's unroll-8 loop needs no remainder)
__global__ __launch_bounds__(1024) void scan_kernel(const int* __restrict__ cnt,
                                                    int* __restrict__ base,
                                                    int* __restrict__ fc, int n) {
    __shared__ int wsum[16];
    __shared__ int carry_s;
    int tid = threadIdx.x;
    int lane = tid & 63, wid = tid >> 6;
    if (tid == 0) carry_s = 0;
    __syncthreads();
    for (int s = 0; s < n; s += 4096) {
        int i0 = s + tid * 4;
        int v0 = 0, v1 = 0, v2 = 0, v3 = 0;
        if (i0 + 3 < n) {
            int4 q = *(const int4*)(cnt + i0);
            v0 = q.x; v1 = q.y; v2 = q.z; v3 = q.w;
        } else if (i0 < n) {
            v0 = cnt[i0];
            if (i0 + 1 < n) v1 = cnt[i0 + 1];
            if (i0 + 2 < n) v2 = cnt[i0 + 2];
        }
        v0 = (v0 + 7) & ~7; v1 = (v1 + 7) & ~7;
        v2 = (v2 + 7) & ~7; v3 = (v3 + 7) & ~7;
        int tsum = v0 + v1 + v2 + v3;
        int incl = tsum;
#pragma unroll
        for (int off = 1; off < 64; off <<= 1) {
            int t = __shfl_up(incl, off, 64);
            if (lane >= off) incl += t;
        }
        if (lane == 63) wsum[wid] = incl;
        __syncthreads();                      // wsum visible
        int add = carry_s;
#pragma unroll
        for (int w = 0; w < 16; ++w) if (w < wid) add += wsum[w];
        int run = add + incl - tsum;          // exclusive prefix of this thread's 4
        if (i0 + 0 < n) { base[i0 + 0] = run; fc[i0 + 0] = run; } run += v0;
        if (i0 + 1 < n) { base[i0 + 1] = run; fc[i0 + 1] = run; } run += v1;
        if (i0 + 2 < n) { base[i0 + 2] = run; fc[i0 + 2] = run; } run += v2;
        if (i0 + 3 < n) { base[i0 + 3] = run; fc[i0 + 3] = run; }
        __syncthreads();                      // all reads of carry_s/wsum done
        if (tid == 1023) carry_s = add + incl;
        __syncthreads();                      // carry_s visible
    }
    if (tid == 0) base[n] = carry_s;
}

// ---------------- fill padded CSR buckets with fused (row, norm) pairs ----------------
// fill_cnt pre-seeded with the padded bucket base -> atomicAdd alone gives the slot.
// pad slots keep their memset value (row=0, norm=0.0f): exact no-op in agg.
__global__ __launch_bounds__(256) void fill_kernel(
        const int* __restrict__ ei, const float* __restrict__ ea,
        const float* __restrict__ dis,
        const float* __restrict__ conf_w, const float* __restrict__ conf_b,
        int* __restrict__ fill_cnt, int2* __restrict__ rn_sorted, int E) {
    int e = blockIdx.x * 256 + threadIdx.x;
    if (e >= E) return;
    int row = ei[e];
    int col = ei[E + e];
    float w = ea[(size_t)e*3+0]*conf_w[0] + ea[(size_t)e*3+1]*conf_w[1]
            + ea[(size_t)e*3+2]*conf_w[2] + conf_b[0];
    w = 1.0f / (1.0f + __expf(-w));               // sigmoid
    float nm = dis[row] * dis[col] * w;
    int pos = atomicAdd(&fill_cnt[col], 1);
    rn_sorted[pos] = make_int2(row, __float_as_int(nm));
}

// ------- gather-aggregate (bf16): aggh[node] = sum over bucket xh[row]*norm -------
// one WAVE per node; lane owns 8 channels (16B gather/edge). Buckets padded to x8:
// branchless unroll-8 main loop, next group's (row,norm) pairs prefetched while the
// current group's 8 gathers are in flight -> index-load latency fully hidden,
// 8KB of gathers in flight per wave.
#define ACC8(u, nm)                                                     \
    a0 = fmaf(bflo((u).x), (nm), a0); a1 = fmaf(bfhi((u).x), (nm), a1); \
    a2 = fmaf(bflo((u).y), (nm), a2); a3 = fmaf(bfhi((u).y), (nm), a3); \
    a4 = fmaf(bflo((u).z), (nm), a4); a5 = fmaf(bfhi((u).z), (nm), a5); \
    a6 = fmaf(bflo((u).w), (nm), a6); a7 = fmaf(bfhi((u).w), (nm), a7);

__global__ __launch_bounds__(256) void agg_kernel(
        const ushort* __restrict__ xh, const int2* __restrict__ rn,
        const int* __restrict__ base, ushort* __restrict__ aggh, int N) {
    int wid  = threadIdx.x >> 6;
    int lane = threadIdx.x & 63;
    int node = blockIdx.x * 4 + wid;
    if (node >= N) return;
    int start = base[node], end = base[node + 1];
    const ushort* xc = xh + lane * 8;             // this lane's 8-channel slice
    float a0 = 0.f, a1 = 0.f, a2 = 0.f, a3 = 0.f;
    float a4 = 0.f, a5 = 0.f, a6 = 0.f, a7 = 0.f;
    int p = start;
    if (p < end) {
        int2 e0 = rn[p+0], e1 = rn[p+1], e2 = rn[p+2], e3 = rn[p+3];
        int2 e4 = rn[p+4], e5 = rn[p+5], e6 = rn[p+6], e7 = rn[p+7];
        for (;;) {
            // issue the 8 gathers for the current group
            uint4 u0 = *(const uint4*)(xc + ((size_t)e0.x << 9));
            uint4 u1 = *(const uint4*)(xc + ((size_t)e1.x << 9));
            uint4 u2 = *(const uint4*)(xc + ((size_t)e2.x << 9));
            uint4 u3 = *(const uint4*)(xc + ((size_t)e3.x << 9));
            uint4 u4 = *(const uint4*)(xc + ((size_t)e4.x << 9));
            uint4 u5 = *(const uint4*)(xc + ((size_t)e5.x << 9));
            uint4 u6 = *(const uint4*)(xc + ((size_t)e6.x << 9));
            uint4 u7 = *(const uint4*)(xc + ((size_t)e7.x << 9));
            p += 8;
            // prefetch next group's indices (branchless: dummy reload on last iter)
            int q = (p < end) ? p : start;
            int2 f0 = rn[q+0], f1 = rn[q+1], f2 = rn[q+2], f3 = rn[q+3];
            int2 f4 = rn[q+4], f5 = rn[q+5], f6 = rn[q+6], f7 = rn[q+7];
            float n0 = __int_as_float(e0.y), n1 = __int_as_float(e1.y);
            float n2 = __int_as_float(e2.y), n3 = __int_as_float(e3.y);
            float n4 = __int_as_float(e4.y), n5 = __int_as_float(e5.y);
            float n6 = __int_as_float(e6.y), n7 = __int_as_float(e7.y);
            ACC8(u0, n0); ACC8(u1, n1); ACC8(u2, n2); ACC8(u3, n3);
            ACC8(u4, n4); ACC8(u5, n5); ACC8(u6, n6); ACC8(u7, n7);
            if (p >= end) break;
            e0 = f0; e1 = f1; e2 = f2; e3 = f3;
            e4 = f4; e5 = f5; e6 = f6; e7 = f7;
        }
    }
    uint4 o;
    o.x = packbf(a0, a1);
    o.y = packbf(a2, a3);
    o.z = packbf(a4, a5);
    o.w = packbf(a6, a7);
    *(uint4*)(aggh + (size_t)node * NDIM + lane * 8) = o;
}

// ---------------- bf16 MFMA GEMM (m97 structure): out = A @ B^T + bias ----------------
// 128x128 tile, BK=32, 256 threads = 4 waves, global_load_lds 16B staging.
// 1-D grid with XCD-aware swizzle: the 4 n-blocks of one m-tile land on the SAME XCD
// within a 32-block dispatch window -> A tile fetched from HBM once, 3x L2-hit.
__global__ __launch_bounds__(256) void mfma_gemm(
        const ushort* __restrict__ A,   // [M][512] bf16 (agg)
        const ushort* __restrict__ B,   // [512][512] bf16, row = n (out), col = k (in)
        const float* __restrict__ bias,
        float* __restrict__ out, int M) {
    __shared__ ushort As[128 * 32];     // 8 KB
    __shared__ ushort Bs[128 * 32];     // 8 KB
    int Mb = (M + 127) >> 7;
    int lin = blockIdx.x;
    int full = (Mb >> 3) << 5;          // (Mb/8)*32 blocks in full swizzle groups
    int mb, nb;
    if (lin < full) {
        mb = ((lin >> 5) << 3) + (lin & 7);   // same XCD slot for all 4 nb of this mb
        nb = (lin >> 3) & 3;
    } else {
        int r = lin - full;
        int mrem = Mb & 7;
        mb = ((Mb >> 3) << 3) + (r % mrem);
        nb = r / mrem;
    }
    int m0 = mb << 7;
    int n0 = nb << 7;
    int tid  = threadIdx.x;
    int lane = tid & 63;
    int wave = tid >> 6;
    int wr = wave >> 1, wc = wave & 1;    // wave's 64x64 origin (wr*64, wc*64)
    int quad = lane >> 4, l16 = lane & 15;
    int lrow = lane >> 2, lcol = (lane & 3) << 3;   // staging: row-in-chunk, k-offset

    f32x4 acc[4][4] = {};                  // [mt][nt]

    for (int k0 = 0; k0 < NDIM; k0 += 32) {
        // stage A,B tiles: 8 chunks each of 16 rows x 32 k (1 KB); wave w does chunks 2w,2w+1
#pragma unroll
        for (int i = 0; i < 2; ++i) {
            int ch = wave * 2 + i;          // 0..7
            int r  = ch * 16 + lrow;        // 0..127
            int gm = m0 + r; if (gm >= M) gm = M - 1;   // clamp: junk rows never stored
            gload16(A + ((size_t)gm << 9) + k0 + lcol, &As[ch * 512]);
            gload16(B + ((size_t)(n0 + r) << 9) + k0 + lcol, &Bs[ch * 512]);
        }
        __syncthreads();
#pragma unroll
        for (int mt = 0; mt < 4; ++mt) {
            bf16x8 a = *(const bf16x8*)&As[(wr * 64 + mt * 16 + l16) * 32 + quad * 8];
#pragma unroll
            for (int nt = 0; nt < 4; ++nt) {
                bf16x8 b = *(const bf16x8*)&Bs[(wc * 64 + nt * 16 + l16) * 32 + quad * 8];
                acc[mt][nt] = __builtin_amdgcn_mfma_f32_16x16x32_bf16(a, b, acc[mt][nt], 0, 0, 0);
            }
        }
        __syncthreads();
    }
    // epilogue: C/D layout col = lane&15, row = quad*4 + reg
#pragma unroll
    for (int mt = 0; mt < 4; ++mt) {
#pragma unroll
        for (int nt = 0; nt < 4; ++nt) {
            int gn = n0 + wc * 64 + nt * 16 + l16;
            float bv = bias[gn];
#pragma unroll
            for (int r = 0; r < 4; ++r) {
                int gm = m0 + wr * 64 + mt * 16 + quad * 4 + r;
                if (gm < M) out[(size_t)gm * NDIM + gn] = acc[mt][nt][r] + bv;
            }
        }
    }
}

extern "C" void kernel_launch(void* const* d_in, const int* in_sizes, int n_in,
                              void* d_out, int out_size, void* d_ws, size_t ws_size,
                              hipStream_t stream) {
    const float* x      = (const float*)d_in[0];
    const int*   ei     = (const int*)  d_in[1];   // edge_index [2][E]
    const float* ea     = (const float*)d_in[2];   // edge_attr [E][3]
    const float* lin_w  = (const float*)d_in[3];   // [512][512]
    const float* lin_b  = (const float*)d_in[4];   // [512]
    const float* conf_w = (const float*)d_in[5];   // [3]
    const float* conf_b = (const float*)d_in[6];   // [1]
    float* out = (float*)d_out;

    int N = in_sizes[0] / NDIM;   // 50000
    int E = in_sizes[2] / 3;      // 800000

    // ---- workspace layout (256B aligned slabs) ----
    char* p = (char*)d_ws;
    auto alloc = [&](size_t bytes) {
        char* q = p;
        p += (bytes + 255) & ~(size_t)255;
        return q;
    };
    ushort* aggh       = (ushort*)alloc((size_t)N * NDIM * sizeof(ushort)); // 51.2 MB
    ushort* wh         = (ushort*)alloc((size_t)NDIM * NDIM * sizeof(ushort));
    int*   deg_row     = (int*)  alloc((size_t)N * sizeof(int));            // zeroed slab start
    int*   cnt_col     = (int*)  alloc((size_t)N * sizeof(int));
    int*   fill_cnt    = (int*)  alloc((size_t)N * sizeof(int));
    float* dis         = (float*)alloc((size_t)N * sizeof(float));
    int*   base        = (int*)  alloc((size_t)(N + 1) * sizeof(int));
    size_t rn_cap      = (size_t)E + 7 * (size_t)N + 8;                     // padded worst case
    int2*  rn_sorted   = (int2*) alloc(rn_cap * sizeof(int2));              // zeroed slab end

    // xh (bf16 x, 51.2 MB) lives in the d_out buffer (102.4 MB): consumed by agg_kernel,
    // which completes (stream order) before mfma_gemm writes out.
    ushort* xh = (ushort*)d_out;

    // zero counters + the padded rn buffer (pad slots must read as row=0, norm=0)
    size_t zero_bytes = (size_t)((char*)(rn_sorted + rn_cap) - (char*)deg_row);
    (void)hipMemsetAsync(deg_row, 0, zero_bytes, stream);

    int gE = (E + 255) / 256;
    int gN = (N + 255) / 256;
    int x4 = (N * NDIM) / 4, w4 = (NDIM * NDIM) / 4;
    f2bf_kernel  <<<(x4 + 255) / 256, 256, 0, stream>>>(x, xh, x4);
    f2bf_kernel  <<<(w4 + 255) / 256, 256, 0, stream>>>(lin_w, wh, w4);
    hist_kernel  <<<gE, 256, 0, stream>>>(ei, deg_row, cnt_col, E);
    rsqrt_kernel <<<gN, 256, 0, stream>>>(deg_row, dis, N);
    scan_kernel  <<<1, 1024, 0, stream>>>(cnt_col, base, fill_cnt, N);
    fill_kernel  <<<gE, 256, 0, stream>>>(ei, ea, dis, conf_w, conf_b,
                                          fill_cnt, rn_sorted, E);
    agg_kernel   <<<(N + 3) / 4, 256, 0, stream>>>(xh, rn_sorted, base, aggh, N);
    int Mb = (N + 127) >> 7;
    mfma_gemm    <<<Mb * 4, 256, 0, stream>>>(aggh, wh, lin_b, out, N);
}

// Round 3
// 495.882 us; speedup vs baseline: 1.0182x; 1.0182x over previous
//
#include <hip/hip_runtime.h>

#define NDIM 512   // D_IN == D_OUT == 512

typedef __bf16 bf16x8 __attribute__((ext_vector_type(8)));
typedef float  f32x4  __attribute__((ext_vector_type(4)));

__device__ inline ushort f2bf(float f) {           // fp32 -> bf16 RNE
    uint b = __float_as_uint(f);
    return (ushort)((b + 0x7fffu + ((b >> 16) & 1u)) >> 16);
}
__device__ inline float bflo(uint u) { return __uint_as_float(u << 16); }
__device__ inline float bfhi(uint u) { return __uint_as_float(u & 0xffff0000u); }
__device__ inline uint packbf(float lo, float hi) {
    return ((uint)f2bf(hi) << 16) | (uint)f2bf(lo);
}

// async global->LDS, 16B per lane; lds base must be wave-uniform (dest = base + lane*16)
__device__ inline void gload16(const ushort* g, ushort* l) {
    __builtin_amdgcn_global_load_lds(
        (const __attribute__((address_space(1))) uint*)g,
        (__attribute__((address_space(3))) uint*)l, 16, 0, 0);
}

// -------- fused pre-work: f2bf(x), f2bf(lin_w), histograms -- one launch --------
// block-range partition: [0,gX) convert x, [gX,gX+gW) convert w, rest histogram
__global__ __launch_bounds__(256) void prep_kernel(
        const float* __restrict__ x,  ushort* __restrict__ xh,
        const float* __restrict__ w,  ushort* __restrict__ wh,
        const int* __restrict__ ei, int* __restrict__ deg_row,
        int* __restrict__ cnt_col,
        int nx4, int nw4, int E, int gX, int gW) {
    int b = blockIdx.x;
    if (b < gX) {
        int i = b * 256 + threadIdx.x;
        if (i < nx4) {
            float4 v = ((const float4*)x)[i];
            ushort4 o;
            o.x = f2bf(v.x); o.y = f2bf(v.y); o.z = f2bf(v.z); o.w = f2bf(v.w);
            ((ushort4*)xh)[i] = o;
        }
    } else if (b < gX + gW) {
        int i = (b - gX) * 256 + threadIdx.x;
        if (i < nw4) {
            float4 v = ((const float4*)w)[i];
            ushort4 o;
            o.x = f2bf(v.x); o.y = f2bf(v.y); o.z = f2bf(v.z); o.w = f2bf(v.w);
            ((ushort4*)wh)[i] = o;
        }
    } else {
        int e = (b - gX - gW) * 256 + threadIdx.x;
        if (e < E) {
            atomicAdd(&deg_row[ei[e]], 1);
            atomicAdd(&cnt_col[ei[E + e]], 1);
        }
    }
}

// ------- single-block exclusive scan over PADDED counts pc=(cnt+7)&~7 -------
// base[i] = fill_cnt[i] = exclusive prefix; base[n] = padded total.
__global__ __launch_bounds__(1024) void scan_kernel(const int* __restrict__ cnt,
                                                    int* __restrict__ base,
                                                    int* __restrict__ fc, int n) {
    __shared__ int wsum[16];
    __shared__ int carry_s;
    int tid = threadIdx.x;
    int lane = tid & 63, wid = tid >> 6;
    if (tid == 0) carry_s = 0;
    __syncthreads();
    for (int s = 0; s < n; s += 4096) {
        int i0 = s + tid * 4;
        int v0 = 0, v1 = 0, v2 = 0, v3 = 0;
        if (i0 + 3 < n) {
            int4 q = *(const int4*)(cnt + i0);
            v0 = q.x; v1 = q.y; v2 = q.z; v3 = q.w;
        } else if (i0 < n) {
            v0 = cnt[i0];
            if (i0 + 1 < n) v1 = cnt[i0 + 1];
            if (i0 + 2 < n) v2 = cnt[i0 + 2];
        }
        v0 = (v0 + 7) & ~7; v1 = (v1 + 7) & ~7;
        v2 = (v2 + 7) & ~7; v3 = (v3 + 7) & ~7;
        int tsum = v0 + v1 + v2 + v3;
        int incl = tsum;
#pragma unroll
        for (int off = 1; off < 64; off <<= 1) {
            int t = __shfl_up(incl, off, 64);
            if (lane >= off) incl += t;
        }
        if (lane == 63) wsum[wid] = incl;
        __syncthreads();                      // wsum visible
        int add = carry_s;
#pragma unroll
        for (int w = 0; w < 16; ++w) if (w < wid) add += wsum[w];
        int run = add + incl - tsum;          // exclusive prefix of this thread's 4
        if (i0 + 0 < n) { base[i0 + 0] = run; fc[i0 + 0] = run; } run += v0;
        if (i0 + 1 < n) { base[i0 + 1] = run; fc[i0 + 1] = run; } run += v1;
        if (i0 + 2 < n) { base[i0 + 2] = run; fc[i0 + 2] = run; } run += v2;
        if (i0 + 3 < n) { base[i0 + 3] = run; fc[i0 + 3] = run; }
        __syncthreads();                      // all reads of carry_s/wsum done
        if (tid == 1023) carry_s = add + incl;
        __syncthreads();                      // carry_s visible
    }
    if (tid == 0) base[n] = carry_s;
}

// ---------------- fill padded CSR buckets with fused (row, norm) pairs ----------------
// rsqrt folded in: reads deg_row for both endpoints (dis array + kernel removed).
// fill_cnt pre-seeded with padded bucket base -> atomicAdd alone gives the slot.
// pad slots keep their memset value (row=0, norm=0.0f): exact no-op in agg.
__global__ __launch_bounds__(256) void fill_kernel(
        const int* __restrict__ ei, const float* __restrict__ ea,
        const int* __restrict__ deg,
        const float* __restrict__ conf_w, const float* __restrict__ conf_b,
        int* __restrict__ fill_cnt, int2* __restrict__ rn_sorted, int E) {
    int e = blockIdx.x * 256 + threadIdx.x;
    if (e >= E) return;
    int row = ei[e];
    int col = ei[E + e];
    float w = ea[(size_t)e*3+0]*conf_w[0] + ea[(size_t)e*3+1]*conf_w[1]
            + ea[(size_t)e*3+2]*conf_w[2] + conf_b[0];
    w = 1.0f / (1.0f + __expf(-w));               // sigmoid
    int dr = deg[row], dc = deg[col];
    float ir = (dr > 0) ? rsqrtf((float)dr) : 0.0f;
    float ic = (dc > 0) ? rsqrtf((float)dc) : 0.0f;
    float nm = ir * ic * w;
    int pos = atomicAdd(&fill_cnt[col], 1);
    rn_sorted[pos] = make_int2(row, __float_as_int(nm));
}

// ------- gather-aggregate (bf16): aggh[node] = sum over bucket xh[row]*norm -------
// one WAVE per node; buckets padded to x8. Each group of 8 edges is staged into a
// per-wave private 8KB LDS slab via global_load_lds (zero VGPR cost -> the compiler
// CANNOT re-serialize: all 8 row loads are in flight before the single vmcnt wait
// it inserts ahead of the first ds_read). Next group's (row,norm) pairs load while
// the gathers fly. No barriers (slab is wave-private).
#define ACC8(u, nm)                                                     \
    a0 = fmaf(bflo((u).x), (nm), a0); a1 = fmaf(bfhi((u).x), (nm), a1); \
    a2 = fmaf(bflo((u).y), (nm), a2); a3 = fmaf(bfhi((u).y), (nm), a3); \
    a4 = fmaf(bflo((u).z), (nm), a4); a5 = fmaf(bfhi((u).z), (nm), a5); \
    a6 = fmaf(bflo((u).w), (nm), a6); a7 = fmaf(bfhi((u).w), (nm), a7);

__global__ __launch_bounds__(256) void agg_kernel(
        const ushort* __restrict__ xh, const int2* __restrict__ rn,
        const int* __restrict__ base, ushort* __restrict__ aggh, int N) {
    __shared__ ushort stage[4 * 8 * 512];          // 32 KB: 4 waves x 8 rows x 1KB
    int wid  = threadIdx.x >> 6;
    int lane = threadIdx.x & 63;
    int node = blockIdx.x * 4 + wid;
    if (node >= N) return;
    int start = base[node], end = base[node + 1];
    ushort* buf = stage + wid * (8 * 512);
    const size_t loff = (size_t)lane * 8;          // lane's 16B slice within a row
    float a0 = 0.f, a1 = 0.f, a2 = 0.f, a3 = 0.f;
    float a4 = 0.f, a5 = 0.f, a6 = 0.f, a7 = 0.f;
    int p = start;
    if (p < end) {
        // (row,norm) pairs for group 0: 4 x int4 (64B aligned: bases are x8 pairs)
        int4 q0 = *(const int4*)(rn + p + 0);
        int4 q1 = *(const int4*)(rn + p + 2);
        int4 q2 = *(const int4*)(rn + p + 4);
        int4 q3 = *(const int4*)(rn + p + 6);
        for (;;) {
            // issue 8 async 1KB row-gathers into this wave's LDS slab
            gload16(xh + ((size_t)(uint)q0.x << 9) + loff, buf + 0 * 512);
            gload16(xh + ((size_t)(uint)q0.z << 9) + loff, buf + 1 * 512);
            gload16(xh + ((size_t)(uint)q1.x << 9) + loff, buf + 2 * 512);
            gload16(xh + ((size_t)(uint)q1.z << 9) + loff, buf + 3 * 512);
            gload16(xh + ((size_t)(uint)q2.x << 9) + loff, buf + 4 * 512);
            gload16(xh + ((size_t)(uint)q2.z << 9) + loff, buf + 5 * 512);
            gload16(xh + ((size_t)(uint)q3.x << 9) + loff, buf + 6 * 512);
            gload16(xh + ((size_t)(uint)q3.z << 9) + loff, buf + 7 * 512);
            float n0 = __int_as_float(q0.y), n1 = __int_as_float(q0.w);
            float n2 = __int_as_float(q1.y), n3 = __int_as_float(q1.w);
            float n4 = __int_as_float(q2.y), n5 = __int_as_float(q2.w);
            float n6 = __int_as_float(q3.y), n7 = __int_as_float(q3.w);
            p += 8;
            bool more = p < end;
            int q = more ? p : start;              // dummy reload on last iter
            q0 = *(const int4*)(rn + q + 0);
            q1 = *(const int4*)(rn + q + 2);
            q2 = *(const int4*)(rn + q + 4);
            q3 = *(const int4*)(rn + q + 6);
            // consume staged rows (compiler inserts the vmcnt wait before ds_read)
            uint4 u;
            u = *(const uint4*)(buf + 0 * 512 + loff); ACC8(u, n0);
            u = *(const uint4*)(buf + 1 * 512 + loff); ACC8(u, n1);
            u = *(const uint4*)(buf + 2 * 512 + loff); ACC8(u, n2);
            u = *(const uint4*)(buf + 3 * 512 + loff); ACC8(u, n3);
            u = *(const uint4*)(buf + 4 * 512 + loff); ACC8(u, n4);
            u = *(const uint4*)(buf + 5 * 512 + loff); ACC8(u, n5);
            u = *(const uint4*)(buf + 6 * 512 + loff); ACC8(u, n6);
            u = *(const uint4*)(buf + 7 * 512 + loff); ACC8(u, n7);
            if (!more) break;
        }
    }
    uint4 o;
    o.x = packbf(a0, a1);
    o.y = packbf(a2, a3);
    o.z = packbf(a4, a5);
    o.w = packbf(a6, a7);
    *(uint4*)(aggh + (size_t)node * NDIM + loff) = o;
}

// ---------------- bf16 MFMA GEMM (m97 structure): out = A @ B^T + bias ----------------
// 128x128 tile, BK=32, 256 threads = 4 waves, global_load_lds 16B staging.
// 1-D grid with XCD-aware swizzle: the 4 n-blocks of one m-tile land on the SAME XCD
// within a 32-block dispatch window -> A tile fetched from HBM once, 3x L2-hit.
__global__ __launch_bounds__(256) void mfma_gemm(
        const ushort* __restrict__ A,   // [M][512] bf16 (agg)
        const ushort* __restrict__ B,   // [512][512] bf16, row = n (out), col = k (in)
        const float* __restrict__ bias,
        float* __restrict__ out, int M) {
    __shared__ ushort As[128 * 32];     // 8 KB
    __shared__ ushort Bs[128 * 32];     // 8 KB
    int Mb = (M + 127) >> 7;
    int lin = blockIdx.x;
    int full = (Mb >> 3) << 5;          // (Mb/8)*32 blocks in full swizzle groups
    int mb, nb;
    if (lin < full) {
        mb = ((lin >> 5) << 3) + (lin & 7);   // same XCD slot for all 4 nb of this mb
        nb = (lin >> 3) & 3;
    } else {
        int r = lin - full;
        int mrem = Mb & 7;
        mb = ((Mb >> 3) << 3) + (r % mrem);
        nb = r / mrem;
    }
    int m0 = mb << 7;
    int n0 = nb << 7;
    int tid  = threadIdx.x;
    int lane = tid & 63;
    int wave = tid >> 6;
    int wr = wave >> 1, wc = wave & 1;    // wave's 64x64 origin (wr*64, wc*64)
    int quad = lane >> 4, l16 = lane & 15;
    int lrow = lane >> 2, lcol = (lane & 3) << 3;   // staging: row-in-chunk, k-offset

    f32x4 acc[4][4] = {};                  // [mt][nt]

    for (int k0 = 0; k0 < NDIM; k0 += 32) {
        // stage A,B tiles: 8 chunks each of 16 rows x 32 k (1 KB); wave w does chunks 2w,2w+1
#pragma unroll
        for (int i = 0; i < 2; ++i) {
            int ch = wave * 2 + i;          // 0..7
            int r  = ch * 16 + lrow;        // 0..127
            int gm = m0 + r; if (gm >= M) gm = M - 1;   // clamp: junk rows never stored
            gload16(A + ((size_t)gm << 9) + k0 + lcol, &As[ch * 512]);
            gload16(B + ((size_t)(n0 + r) << 9) + k0 + lcol, &Bs[ch * 512]);
        }
        __syncthreads();
#pragma unroll
        for (int mt = 0; mt < 4; ++mt) {
            bf16x8 a = *(const bf16x8*)&As[(wr * 64 + mt * 16 + l16) * 32 + quad * 8];
#pragma unroll
            for (int nt = 0; nt < 4; ++nt) {
                bf16x8 b = *(const bf16x8*)&Bs[(wc * 64 + nt * 16 + l16) * 32 + quad * 8];
                acc[mt][nt] = __builtin_amdgcn_mfma_f32_16x16x32_bf16(a, b, acc[mt][nt], 0, 0, 0);
            }
        }
        __syncthreads();
    }
    // epilogue: C/D layout col = lane&15, row = quad*4 + reg
#pragma unroll
    for (int mt = 0; mt < 4; ++mt) {
#pragma unroll
        for (int nt = 0; nt < 4; ++nt) {
            int gn = n0 + wc * 64 + nt * 16 + l16;
            float bv = bias[gn];
#pragma unroll
            for (int r = 0; r < 4; ++r) {
                int gm = m0 + wr * 64 + mt * 16 + quad * 4 + r;
                if (gm < M) out[(size_t)gm * NDIM + gn] = acc[mt][nt][r] + bv;
            }
        }
    }
}

extern "C" void kernel_launch(void* const* d_in, const int* in_sizes, int n_in,
                              void* d_out, int out_size, void* d_ws, size_t ws_size,
                              hipStream_t stream) {
    const float* x      = (const float*)d_in[0];
    const int*   ei     = (const int*)  d_in[1];   // edge_index [2][E]
    const float* ea     = (const float*)d_in[2];   // edge_attr [E][3]
    const float* lin_w  = (const float*)d_in[3];   // [512][512]
    const float* lin_b  = (const float*)d_in[4];   // [512]
    const float* conf_w = (const float*)d_in[5];   // [3]
    const float* conf_b = (const float*)d_in[6];   // [1]
    float* out = (float*)d_out;

    int N = in_sizes[0] / NDIM;   // 50000
    int E = in_sizes[2] / 3;      // 800000

    // ---- workspace layout (256B aligned slabs) ----
    char* p = (char*)d_ws;
    auto alloc = [&](size_t bytes) {
        char* q = p;
        p += (bytes + 255) & ~(size_t)255;
        return q;
    };
    ushort* aggh       = (ushort*)alloc((size_t)N * NDIM * sizeof(ushort)); // 51.2 MB
    ushort* wh         = (ushort*)alloc((size_t)NDIM * NDIM * sizeof(ushort));
    int*   deg_row     = (int*)  alloc((size_t)N * sizeof(int));            // zeroed slab start
    int*   cnt_col     = (int*)  alloc((size_t)N * sizeof(int));
    int*   fill_cnt    = (int*)  alloc((size_t)N * sizeof(int));
    int*   base        = (int*)  alloc((size_t)(N + 1) * sizeof(int));
    size_t rn_cap      = (size_t)E + 7 * (size_t)N + 8;                     // padded worst case
    int2*  rn_sorted   = (int2*) alloc(rn_cap * sizeof(int2));              // zeroed slab end

    // xh (bf16 x, 51.2 MB) lives in the d_out buffer (102.4 MB): consumed by agg_kernel,
    // which completes (stream order) before mfma_gemm writes out.
    ushort* xh = (ushort*)d_out;

    // one memset covers counters + base + padded rn buffer (pad slots = row 0, norm 0)
    size_t zero_bytes = (size_t)((char*)(rn_sorted + rn_cap) - (char*)deg_row);
    (void)hipMemsetAsync(deg_row, 0, zero_bytes, stream);

    int gE = (E + 255) / 256;
    int x4 = (N * NDIM) / 4, w4 = (NDIM * NDIM) / 4;
    int gX = (x4 + 255) / 256, gW = (w4 + 255) / 256;
    prep_kernel  <<<gX + gW + gE, 256, 0, stream>>>(x, xh, lin_w, wh, ei,
                                                    deg_row, cnt_col, x4, w4, E, gX, gW);
    scan_kernel  <<<1, 1024, 0, stream>>>(cnt_col, base, fill_cnt, N);
    fill_kernel  <<<gE, 256, 0, stream>>>(ei, ea, deg_row, conf_w, conf_b,
                                          fill_cnt, rn_sorted, E);
    agg_kernel   <<<(N + 3) / 4, 256, 0, stream>>>(xh, rn_sorted, base, aggh, N);
    int Mb = (N + 127) >> 7;
    mfma_gemm    <<<Mb * 4, 256, 0, stream>>>(aggh, wh, lin_b, out, N);
}

// Round 4
// 436.311 us; speedup vs baseline: 1.1572x; 1.1365x over previous
//
#include <hip/hip_runtime.h>

#define NDIM 512   // D_IN == D_OUT == 512
#define CAP  64    // fixed bucket capacity (mean deg 16, P(deg>64) ~ 1e-58)

typedef __bf16 bf16x8 __attribute__((ext_vector_type(8)));
typedef float  f32x4  __attribute__((ext_vector_type(4)));

__device__ inline ushort f2bf(float f) {           // fp32 -> bf16 RNE
    uint b = __float_as_uint(f);
    return (ushort)((b + 0x7fffu + ((b >> 16) & 1u)) >> 16);
}
__device__ inline float bflo(uint u) { return __uint_as_float(u << 16); }
__device__ inline float bfhi(uint u) { return __uint_as_float(u & 0xffff0000u); }
__device__ inline uint packbf(float lo, float hi) {
    return ((uint)f2bf(hi) << 16) | (uint)f2bf(lo);
}

// async global->LDS, 16B per lane; lds base must be wave-uniform (dest = base + lane*16)
__device__ inline void gload16(const ushort* g, ushort* l) {
    __builtin_amdgcn_global_load_lds(
        (const __attribute__((address_space(1))) uint*)g,
        (__attribute__((address_space(3))) uint*)l, 16, 0, 0);
}

// -------- fused pre-work: f2bf(x), f2bf(lin_w), deg_row histogram -- one launch --------
// block-range partition: [0,gX) convert x, [gX,gX+gW) convert w, rest histogram.
// (col counting removed: fill_kernel's atomic bucket counter doubles as the count)
__global__ __launch_bounds__(256) void prep_kernel(
        const float* __restrict__ x,  ushort* __restrict__ xh,
        const float* __restrict__ w,  ushort* __restrict__ wh,
        const int* __restrict__ ei, int* __restrict__ deg_row,
        int nx4, int nw4, int E, int gX, int gW) {
    int b = blockIdx.x;
    if (b < gX) {
        int i = b * 256 + threadIdx.x;
        if (i < nx4) {
            float4 v = ((const float4*)x)[i];
            ushort4 o;
            o.x = f2bf(v.x); o.y = f2bf(v.y); o.z = f2bf(v.z); o.w = f2bf(v.w);
            ((ushort4*)xh)[i] = o;
        }
    } else if (b < gX + gW) {
        int i = (b - gX) * 256 + threadIdx.x;
        if (i < nw4) {
            float4 v = ((const float4*)w)[i];
            ushort4 o;
            o.x = f2bf(v.x); o.y = f2bf(v.y); o.z = f2bf(v.z); o.w = f2bf(v.w);
            ((ushort4*)wh)[i] = o;
        }
    } else {
        int e = (b - gX - gW) * 256 + threadIdx.x;
        if (e < E) atomicAdd(&deg_row[ei[e]], 1);
    }
}

// ---------------- fill fixed-stride buckets with fused (row, norm) pairs ----------------
// bucket for col = rn[col*CAP .. col*CAP+63]; fill_cnt is the per-bucket cursor and,
// after this kernel, the final per-node in-degree count used by agg.
// unused slots keep their memset value (row=0, norm=0.0f): exact no-op in agg.
__global__ __launch_bounds__(256) void fill_kernel(
        const int* __restrict__ ei, const float* __restrict__ ea,
        const int* __restrict__ deg,
        const float* __restrict__ conf_w, const float* __restrict__ conf_b,
        int* __restrict__ fill_cnt, int2* __restrict__ rn, int E) {
    int e = blockIdx.x * 256 + threadIdx.x;
    if (e >= E) return;
    int row = ei[e];
    int col = ei[E + e];
    float w = ea[(size_t)e*3+0]*conf_w[0] + ea[(size_t)e*3+1]*conf_w[1]
            + ea[(size_t)e*3+2]*conf_w[2] + conf_b[0];
    w = 1.0f / (1.0f + __expf(-w));               // sigmoid
    int dr = deg[row], dc = deg[col];
    float ir = (dr > 0) ? rsqrtf((float)dr) : 0.0f;
    float ic = (dc > 0) ? rsqrtf((float)dc) : 0.0f;
    float nm = ir * ic * w;
    int pos = (col << 6) + atomicAdd(&fill_cnt[col], 1);
    rn[pos] = make_int2(row, __float_as_int(nm));
}

// ------- gather-aggregate (bf16): aggh[node] = sum over bucket xh[row]*norm -------
// one WAVE per node; lane owns 8 channels (one 16B uint4 gather per edge). Buckets at
// fixed stride CAP; processed length rounded up to x8 (zeroed pads are no-ops).
// Evidence (R1/R2/R3): this kernel is throughput-bound on the L2-miss path at
// ~3.8 TB/s regardless of in-flight depth -> keep the cheapest (register) form.
#define ACC8(u, nm)                                                     \
    a0 = fmaf(bflo((u).x), (nm), a0); a1 = fmaf(bfhi((u).x), (nm), a1); \
    a2 = fmaf(bflo((u).y), (nm), a2); a3 = fmaf(bfhi((u).y), (nm), a3); \
    a4 = fmaf(bflo((u).z), (nm), a4); a5 = fmaf(bfhi((u).z), (nm), a5); \
    a6 = fmaf(bflo((u).w), (nm), a6); a7 = fmaf(bfhi((u).w), (nm), a7);

__global__ __launch_bounds__(256) void agg_kernel(
        const ushort* __restrict__ xh, const int2* __restrict__ rn,
        const int* __restrict__ cnt, ushort* __restrict__ aggh, int N) {
    int wid  = threadIdx.x >> 6;
    int lane = threadIdx.x & 63;
    int node = blockIdx.x * 4 + wid;
    if (node >= N) return;
    int start = node << 6;                        // CAP=64 stride
    int end   = start + ((cnt[node] + 7) & ~7);   // x8-padded length
    const ushort* xc = xh + lane * 8;             // this lane's 8-channel slice
    float a0 = 0.f, a1 = 0.f, a2 = 0.f, a3 = 0.f;
    float a4 = 0.f, a5 = 0.f, a6 = 0.f, a7 = 0.f;
    int p = start;
    if (p < end) {
        // (row,norm) pairs for group 0: 4 x int4 (64B aligned)
        int4 q0 = *(const int4*)(rn + p + 0);
        int4 q1 = *(const int4*)(rn + p + 2);
        int4 q2 = *(const int4*)(rn + p + 4);
        int4 q3 = *(const int4*)(rn + p + 6);
        for (;;) {
            uint4 u0 = *(const uint4*)(xc + ((size_t)(uint)q0.x << 9));
            uint4 u1 = *(const uint4*)(xc + ((size_t)(uint)q0.z << 9));
            uint4 u2 = *(const uint4*)(xc + ((size_t)(uint)q1.x << 9));
            uint4 u3 = *(const uint4*)(xc + ((size_t)(uint)q1.z << 9));
            uint4 u4 = *(const uint4*)(xc + ((size_t)(uint)q2.x << 9));
            uint4 u5 = *(const uint4*)(xc + ((size_t)(uint)q2.z << 9));
            uint4 u6 = *(const uint4*)(xc + ((size_t)(uint)q3.x << 9));
            uint4 u7 = *(const uint4*)(xc + ((size_t)(uint)q3.z << 9));
            float n0 = __int_as_float(q0.y), n1 = __int_as_float(q0.w);
            float n2 = __int_as_float(q1.y), n3 = __int_as_float(q1.w);
            float n4 = __int_as_float(q2.y), n5 = __int_as_float(q2.w);
            float n6 = __int_as_float(q3.y), n7 = __int_as_float(q3.w);
            p += 8;
            bool more = p < end;
            int q = more ? p : start;             // dummy reload on last iter
            q0 = *(const int4*)(rn + q + 0);
            q1 = *(const int4*)(rn + q + 2);
            q2 = *(const int4*)(rn + q + 4);
            q3 = *(const int4*)(rn + q + 6);
            ACC8(u0, n0); ACC8(u1, n1); ACC8(u2, n2); ACC8(u3, n3);
            ACC8(u4, n4); ACC8(u5, n5); ACC8(u6, n6); ACC8(u7, n7);
            if (!more) break;
        }
    }
    uint4 o;
    o.x = packbf(a0, a1);
    o.y = packbf(a2, a3);
    o.z = packbf(a4, a5);
    o.w = packbf(a6, a7);
    *(uint4*)(aggh + (size_t)node * NDIM + lane * 8) = o;
}

// ---------------- bf16 MFMA GEMM (m97 structure): out = A @ B^T + bias ----------------
// 128x128 tile, BK=32, 256 threads = 4 waves, global_load_lds 16B staging.
// 1-D grid with XCD-aware swizzle: the 4 n-blocks of one m-tile land on the SAME XCD
// within a 32-block dispatch window -> A tile fetched from HBM once, 3x L2-hit.
// (BK=64 rejected by analysis: 128B LDS rows + linear global_load_lds dest would be a
//  16-way read conflict; BK=32's 64B rows alternate bank halves -> conflict-free.)
__global__ __launch_bounds__(256) void mfma_gemm(
        const ushort* __restrict__ A,   // [M][512] bf16 (agg)
        const ushort* __restrict__ B,   // [512][512] bf16, row = n (out), col = k (in)
        const float* __restrict__ bias,
        float* __restrict__ out, int M) {
    __shared__ ushort As[128 * 32];     // 8 KB
    __shared__ ushort Bs[128 * 32];     // 8 KB
    int Mb = (M + 127) >> 7;
    int lin = blockIdx.x;
    int full = (Mb >> 3) << 5;          // (Mb/8)*32 blocks in full swizzle groups
    int mb, nb;
    if (lin < full) {
        mb = ((lin >> 5) << 3) + (lin & 7);   // same XCD slot for all 4 nb of this mb
        nb = (lin >> 3) & 3;
    } else {
        int r = lin - full;
        int mrem = Mb & 7;
        mb = ((Mb >> 3) << 3) + (r % mrem);
        nb = r / mrem;
    }
    int m0 = mb << 7;
    int n0 = nb << 7;
    int tid  = threadIdx.x;
    int lane = tid & 63;
    int wave = tid >> 6;
    int wr = wave >> 1, wc = wave & 1;    // wave's 64x64 origin (wr*64, wc*64)
    int quad = lane >> 4, l16 = lane & 15;
    int lrow = lane >> 2, lcol = (lane & 3) << 3;   // staging: row-in-chunk, k-offset

    f32x4 acc[4][4] = {};                  // [mt][nt]

    for (int k0 = 0; k0 < NDIM; k0 += 32) {
        // stage A,B tiles: 8 chunks each of 16 rows x 32 k (1 KB); wave w does chunks 2w,2w+1
#pragma unroll
        for (int i = 0; i < 2; ++i) {
            int ch = wave * 2 + i;          // 0..7
            int r  = ch * 16 + lrow;        // 0..127
            int gm = m0 + r; if (gm >= M) gm = M - 1;   // clamp: junk rows never stored
            gload16(A + ((size_t)gm << 9) + k0 + lcol, &As[ch * 512]);
            gload16(B + ((size_t)(n0 + r) << 9) + k0 + lcol, &Bs[ch * 512]);
        }
        __syncthreads();
#pragma unroll
        for (int mt = 0; mt < 4; ++mt) {
            bf16x8 a = *(const bf16x8*)&As[(wr * 64 + mt * 16 + l16) * 32 + quad * 8];
#pragma unroll
            for (int nt = 0; nt < 4; ++nt) {
                bf16x8 b = *(const bf16x8*)&Bs[(wc * 64 + nt * 16 + l16) * 32 + quad * 8];
                acc[mt][nt] = __builtin_amdgcn_mfma_f32_16x16x32_bf16(a, b, acc[mt][nt], 0, 0, 0);
            }
        }
        __syncthreads();
    }
    // epilogue: C/D layout col = lane&15, row = quad*4 + reg
#pragma unroll
    for (int mt = 0; mt < 4; ++mt) {
#pragma unroll
        for (int nt = 0; nt < 4; ++nt) {
            int gn = n0 + wc * 64 + nt * 16 + l16;
            float bv = bias[gn];
#pragma unroll
            for (int r = 0; r < 4; ++r) {
                int gm = m0 + wr * 64 + mt * 16 + quad * 4 + r;
                if (gm < M) out[(size_t)gm * NDIM + gn] = acc[mt][nt][r] + bv;
            }
        }
    }
}

extern "C" void kernel_launch(void* const* d_in, const int* in_sizes, int n_in,
                              void* d_out, int out_size, void* d_ws, size_t ws_size,
                              hipStream_t stream) {
    const float* x      = (const float*)d_in[0];
    const int*   ei     = (const int*)  d_in[1];   // edge_index [2][E]
    const float* ea     = (const float*)d_in[2];   // edge_attr [E][3]
    const float* lin_w  = (const float*)d_in[3];   // [512][512]
    const float* lin_b  = (const float*)d_in[4];   // [512]
    const float* conf_w = (const float*)d_in[5];   // [3]
    const float* conf_b = (const float*)d_in[6];   // [1]
    float* out = (float*)d_out;

    int N = in_sizes[0] / NDIM;   // 50000
    int E = in_sizes[2] / 3;      // 800000

    // ---- workspace layout (256B aligned slabs) ----
    char* p = (char*)d_ws;
    auto alloc = [&](size_t bytes) {
        char* q = p;
        p += (bytes + 255) & ~(size_t)255;
        return q;
    };
    ushort* aggh       = (ushort*)alloc((size_t)N * NDIM * sizeof(ushort)); // 51.2 MB
    ushort* wh         = (ushort*)alloc((size_t)NDIM * NDIM * sizeof(ushort));
    int*   deg_row     = (int*)  alloc((size_t)N * sizeof(int));            // zeroed pair
    int*   fill_cnt    = (int*)  alloc((size_t)N * sizeof(int));            // zeroed pair

    // d_out (102.4 MB) double-duty: [0, 51.2M) = xh (bf16 x); [51.2M, 76.8M) = rn buckets.
    // Both are fully consumed by agg_kernel, which completes (stream order) before
    // mfma_gemm writes the final fp32 output over the whole buffer.
    ushort* xh = (ushort*)d_out;
    int2*   rn = (int2*)((char*)d_out + (size_t)N * NDIM * sizeof(ushort));

    size_t zero_cnt_bytes = (size_t)((char*)(fill_cnt + N) - (char*)deg_row);
    (void)hipMemsetAsync(deg_row, 0, zero_cnt_bytes, stream);
    (void)hipMemsetAsync(rn, 0, (size_t)N * CAP * sizeof(int2), stream);    // pads = no-op

    int gE = (E + 255) / 256;
    int x4 = (N * NDIM) / 4, w4 = (NDIM * NDIM) / 4;
    int gX = (x4 + 255) / 256, gW = (w4 + 255) / 256;
    prep_kernel  <<<gX + gW + gE, 256, 0, stream>>>(x, xh, lin_w, wh, ei,
                                                    deg_row, x4, w4, E, gX, gW);
    fill_kernel  <<<gE, 256, 0, stream>>>(ei, ea, deg_row, conf_w, conf_b,
                                          fill_cnt, rn, E);
    agg_kernel   <<<(N + 3) / 4, 256, 0, stream>>>(xh, rn, fill_cnt, aggh, N);
    int Mb = (N + 127) >> 7;
    mfma_gemm    <<<Mb * 4, 256, 0, stream>>>(aggh, wh, lin_b, out, N);
}

// Round 5
// 434.245 us; speedup vs baseline: 1.1627x; 1.0048x over previous
//
#include <hip/hip_runtime.h>

#define NDIM 512   // D_IN == D_OUT == 512
#define CAP  64    // fixed bucket capacity (mean in-deg 16, P(deg>64) ~ 1e-58)

typedef __bf16 bf16x8 __attribute__((ext_vector_type(8)));
typedef float  f32x4  __attribute__((ext_vector_type(4)));

__device__ inline ushort f2bf(float f) {           // fp32 -> bf16 RNE
    uint b = __float_as_uint(f);
    return (ushort)((b + 0x7fffu + ((b >> 16) & 1u)) >> 16);
}
__device__ inline float bflo(uint u) { return __uint_as_float(u << 16); }
__device__ inline float bfhi(uint u) { return __uint_as_float(u & 0xffff0000u); }
__device__ inline uint packbf(float lo, float hi) {
    return ((uint)f2bf(hi) << 16) | (uint)f2bf(lo);
}

// async global->LDS, 16B per lane; lds base must be wave-uniform (dest = base + lane*16)
__device__ inline void gload16(const ushort* g, ushort* l) {
    __builtin_amdgcn_global_load_lds(
        (const __attribute__((address_space(1))) uint*)g,
        (__attribute__((address_space(3))) uint*)l, 16, 0, 0);
}

// -------- fused pre-work (ONE launch): f2bf(x), f2bf(lin_w), deg hist, bucket fill --------
// block-range partition: [0,gX) x-convert | [gX,gX+gW) w-convert | [.., +gE) deg_row hist
// | [.., +gE) fill. fill no longer needs deg (buckets store (row, sigmoid_w) only; the
// rsqrt(deg) factors are applied in agg) -> fill and hist coexist in one launch.
__global__ __launch_bounds__(256) void prep_kernel(
        const float* __restrict__ x,  ushort* __restrict__ xh,
        const float* __restrict__ w,  ushort* __restrict__ wh,
        const int* __restrict__ ei,   const float* __restrict__ ea,
        const float* __restrict__ conf_w, const float* __restrict__ conf_b,
        int* __restrict__ deg_row, int* __restrict__ fill_cnt,
        int2* __restrict__ rn,
        int nx4, int nw4, int E, int gX, int gW, int gE) {
    int b = blockIdx.x;
    if (b < gX) {
        int i = b * 256 + threadIdx.x;
        if (i < nx4) {
            float4 v = ((const float4*)x)[i];
            ushort4 o;
            o.x = f2bf(v.x); o.y = f2bf(v.y); o.z = f2bf(v.z); o.w = f2bf(v.w);
            ((ushort4*)xh)[i] = o;
        }
    } else if (b < gX + gW) {
        int i = (b - gX) * 256 + threadIdx.x;
        if (i < nw4) {
            float4 v = ((const float4*)w)[i];
            ushort4 o;
            o.x = f2bf(v.x); o.y = f2bf(v.y); o.z = f2bf(v.z); o.w = f2bf(v.w);
            ((ushort4*)wh)[i] = o;
        }
    } else if (b < gX + gW + gE) {
        int e = (b - gX - gW) * 256 + threadIdx.x;
        if (e < E) atomicAdd(&deg_row[ei[e]], 1);
    } else {
        int e = (b - gX - gW - gE) * 256 + threadIdx.x;
        if (e < E) {
            int row = ei[e];
            int col = ei[E + e];
            float wv = ea[(size_t)e*3+0]*conf_w[0] + ea[(size_t)e*3+1]*conf_w[1]
                     + ea[(size_t)e*3+2]*conf_w[2] + conf_b[0];
            wv = 1.0f / (1.0f + __expf(-wv));          // sigmoid
            int pos = (col << 6) + atomicAdd(&fill_cnt[col], 1);
            rn[pos] = make_int2(row, __float_as_int(wv));
        }
    }
}

// ------- gather-aggregate: aggh[node] = rsqrt(deg[node]) * sum rsqrt(deg[row])*w*xh[row] -------
// one WAVE per node; lane owns 8 channels (16B uint4 gather/edge). Fixed-stride buckets,
// NO memset: tail slots of each x8 group are masked in-register (row->0 keeps the pad
// gather cache-hot; w->0 + the d>0 rsqrt guard make it an exact no-op).
// deg[row] (200KB, L2-resident) is prefetched one group ahead alongside the index pairs,
// so its ~200cy latency hides under the ~700cy row gathers.
// Evidence (R1-R4): this kernel is throughput-bound on the L2-miss/L3 path at ~3.8 TB/s
// regardless of in-flight depth -> keep the cheapest (register) schedule.
#define ACC8(u, nm)                                                     \
    a0 = fmaf(bflo((u).x), (nm), a0); a1 = fmaf(bfhi((u).x), (nm), a1); \
    a2 = fmaf(bflo((u).y), (nm), a2); a3 = fmaf(bfhi((u).y), (nm), a3); \
    a4 = fmaf(bflo((u).z), (nm), a4); a5 = fmaf(bfhi((u).z), (nm), a5); \
    a6 = fmaf(bflo((u).w), (nm), a6); a7 = fmaf(bfhi((u).w), (nm), a7);

#define LOADQ(P)                                                           \
    q0 = *(const int4*)(rn + (P) + 0);                                     \
    q1 = *(const int4*)(rn + (P) + 2);                                     \
    q2 = *(const int4*)(rn + (P) + 4);                                     \
    q3 = *(const int4*)(rn + (P) + 6);                                     \
    q0.x = ((P)+0 < limit) ? q0.x : 0;  q0.y = ((P)+0 < limit) ? q0.y : 0; \
    q0.z = ((P)+1 < limit) ? q0.z : 0;  q0.w = ((P)+1 < limit) ? q0.w : 0; \
    q1.x = ((P)+2 < limit) ? q1.x : 0;  q1.y = ((P)+2 < limit) ? q1.y : 0; \
    q1.z = ((P)+3 < limit) ? q1.z : 0;  q1.w = ((P)+3 < limit) ? q1.w : 0; \
    q2.x = ((P)+4 < limit) ? q2.x : 0;  q2.y = ((P)+4 < limit) ? q2.y : 0; \
    q2.z = ((P)+5 < limit) ? q2.z : 0;  q2.w = ((P)+5 < limit) ? q2.w : 0; \
    q3.x = ((P)+6 < limit) ? q3.x : 0;  q3.y = ((P)+6 < limit) ? q3.y : 0; \
    q3.z = ((P)+7 < limit) ? q3.z : 0;  q3.w = ((P)+7 < limit) ? q3.w : 0; \
    d0 = deg[(uint)q0.x]; d1 = deg[(uint)q0.z];                            \
    d2 = deg[(uint)q1.x]; d3 = deg[(uint)q1.z];                            \
    d4 = deg[(uint)q2.x]; d5 = deg[(uint)q2.z];                            \
    d6 = deg[(uint)q3.x]; d7 = deg[(uint)q3.z];

__global__ __launch_bounds__(256) void agg_kernel(
        const ushort* __restrict__ xh, const int2* __restrict__ rn,
        const int* __restrict__ cnt_arr, const int* __restrict__ deg,
        ushort* __restrict__ aggh, int N) {
    int wid  = threadIdx.x >> 6;
    int lane = threadIdx.x & 63;
    int node = blockIdx.x * 4 + wid;
    if (node >= N) return;
    int cnt = cnt_arr[node];
    int dc  = deg[node];
    float discol = (dc > 0) ? rsqrtf((float)dc) : 0.0f;
    const ushort* xc = xh + lane * 8;             // this lane's 8-channel slice
    float a0 = 0.f, a1 = 0.f, a2 = 0.f, a3 = 0.f;
    float a4 = 0.f, a5 = 0.f, a6 = 0.f, a7 = 0.f;
    int start = node << 6;                        // CAP=64 stride
    int limit = start + cnt;
    if (cnt > 0) {
        int4 q0, q1, q2, q3;
        int d0, d1, d2, d3, d4, d5, d6, d7;
        int p = start;
        LOADQ(p);
        for (;;) {
            // issue the 8 row gathers for the current group (the long poles)
            uint4 u0 = *(const uint4*)(xc + ((size_t)(uint)q0.x << 9));
            uint4 u1 = *(const uint4*)(xc + ((size_t)(uint)q0.z << 9));
            uint4 u2 = *(const uint4*)(xc + ((size_t)(uint)q1.x << 9));
            uint4 u3 = *(const uint4*)(xc + ((size_t)(uint)q1.z << 9));
            uint4 u4 = *(const uint4*)(xc + ((size_t)(uint)q2.x << 9));
            uint4 u5 = *(const uint4*)(xc + ((size_t)(uint)q2.z << 9));
            uint4 u6 = *(const uint4*)(xc + ((size_t)(uint)q3.x << 9));
            uint4 u7 = *(const uint4*)(xc + ((size_t)(uint)q3.z << 9));
            // snapshot current group's weights + degs before the prefetch overwrites them
            float w0 = __int_as_float(q0.y), w1 = __int_as_float(q0.w);
            float w2 = __int_as_float(q1.y), w3 = __int_as_float(q1.w);
            float w4 = __int_as_float(q2.y), w5 = __int_as_float(q2.w);
            float w6 = __int_as_float(q3.y), w7 = __int_as_float(q3.w);
            int c0 = d0, c1 = d1, c2 = d2, c3 = d3;
            int c4 = d4, c5 = d5, c6 = d6, c7 = d7;
            p += 8;
            bool more = p < limit;
            int np = more ? p : start;            // dummy reload on last iter
            LOADQ(np);
            // per-edge norm: rsqrt(deg[row]) * w  (d>0 guard only matters for masked pads)
            float nm0 = (c0 > 0 ? rsqrtf((float)c0) : 0.f) * w0;
            float nm1 = (c1 > 0 ? rsqrtf((float)c1) : 0.f) * w1;
            float nm2 = (c2 > 0 ? rsqrtf((float)c2) : 0.f) * w2;
            float nm3 = (c3 > 0 ? rsqrtf((float)c3) : 0.f) * w3;
            float nm4 = (c4 > 0 ? rsqrtf((float)c4) : 0.f) * w4;
            float nm5 = (c5 > 0 ? rsqrtf((float)c5) : 0.f) * w5;
            float nm6 = (c6 > 0 ? rsqrtf((float)c6) : 0.f) * w6;
            float nm7 = (c7 > 0 ? rsqrtf((float)c7) : 0.f) * w7;
            ACC8(u0, nm0); ACC8(u1, nm1); ACC8(u2, nm2); ACC8(u3, nm3);
            ACC8(u4, nm4); ACC8(u5, nm5); ACC8(u6, nm6); ACC8(u7, nm7);
            if (!more) break;
        }
    }
    a0 *= discol; a1 *= discol; a2 *= discol; a3 *= discol;
    a4 *= discol; a5 *= discol; a6 *= discol; a7 *= discol;
    uint4 o;
    o.x = packbf(a0, a1);
    o.y = packbf(a2, a3);
    o.z = packbf(a4, a5);
    o.w = packbf(a6, a7);
    *(uint4*)(aggh + (size_t)node * NDIM + lane * 8) = o;
}

// ---------------- bf16 MFMA GEMM (m97 structure): out = A @ B^T + bias ----------------
// 128x128 tile, BK=32, 256 threads = 4 waves, global_load_lds 16B staging.
// 1-D grid with XCD-aware swizzle: the 4 n-blocks of one m-tile land on the SAME XCD
// within a 32-block dispatch window -> A tile fetched from HBM once, 3x L2-hit.
__global__ __launch_bounds__(256) void mfma_gemm(
        const ushort* __restrict__ A,   // [M][512] bf16 (agg)
        const ushort* __restrict__ B,   // [512][512] bf16, row = n (out), col = k (in)
        const float* __restrict__ bias,
        float* __restrict__ out, int M) {
    __shared__ ushort As[128 * 32];     // 8 KB
    __shared__ ushort Bs[128 * 32];     // 8 KB
    int Mb = (M + 127) >> 7;
    int lin = blockIdx.x;
    int full = (Mb >> 3) << 5;          // (Mb/8)*32 blocks in full swizzle groups
    int mb, nb;
    if (lin < full) {
        mb = ((lin >> 5) << 3) + (lin & 7);   // same XCD slot for all 4 nb of this mb
        nb = (lin >> 3) & 3;
    } else {
        int r = lin - full;
        int mrem = Mb & 7;
        mb = ((Mb >> 3) << 3) + (r % mrem);
        nb = r / mrem;
    }
    int m0 = mb << 7;
    int n0 = nb << 7;
    int tid  = threadIdx.x;
    int lane = tid & 63;
    int wave = tid >> 6;
    int wr = wave >> 1, wc = wave & 1;    // wave's 64x64 origin (wr*64, wc*64)
    int quad = lane >> 4, l16 = lane & 15;
    int lrow = lane >> 2, lcol = (lane & 3) << 3;   // staging: row-in-chunk, k-offset

    f32x4 acc[4][4] = {};                  // [mt][nt]

    for (int k0 = 0; k0 < NDIM; k0 += 32) {
        // stage A,B tiles: 8 chunks each of 16 rows x 32 k (1 KB); wave w does chunks 2w,2w+1
#pragma unroll
        for (int i = 0; i < 2; ++i) {
            int ch = wave * 2 + i;          // 0..7
            int r  = ch * 16 + lrow;        // 0..127
            int gm = m0 + r; if (gm >= M) gm = M - 1;   // clamp: junk rows never stored
            gload16(A + ((size_t)gm << 9) + k0 + lcol, &As[ch * 512]);
            gload16(B + ((size_t)(n0 + r) << 9) + k0 + lcol, &Bs[ch * 512]);
        }
        __syncthreads();
#pragma unroll
        for (int mt = 0; mt < 4; ++mt) {
            bf16x8 a = *(const bf16x8*)&As[(wr * 64 + mt * 16 + l16) * 32 + quad * 8];
#pragma unroll
            for (int nt = 0; nt < 4; ++nt) {
                bf16x8 b = *(const bf16x8*)&Bs[(wc * 64 + nt * 16 + l16) * 32 + quad * 8];
                acc[mt][nt] = __builtin_amdgcn_mfma_f32_16x16x32_bf16(a, b, acc[mt][nt], 0, 0, 0);
            }
        }
        __syncthreads();
    }
    // epilogue: C/D layout col = lane&15, row = quad*4 + reg
#pragma unroll
    for (int mt = 0; mt < 4; ++mt) {
#pragma unroll
        for (int nt = 0; nt < 4; ++nt) {
            int gn = n0 + wc * 64 + nt * 16 + l16;
            float bv = bias[gn];
#pragma unroll
            for (int r = 0; r < 4; ++r) {
                int gm = m0 + wr * 64 + mt * 16 + quad * 4 + r;
                if (gm < M) out[(size_t)gm * NDIM + gn] = acc[mt][nt][r] + bv;
            }
        }
    }
}

extern "C" void kernel_launch(void* const* d_in, const int* in_sizes, int n_in,
                              void* d_out, int out_size, void* d_ws, size_t ws_size,
                              hipStream_t stream) {
    const float* x      = (const float*)d_in[0];
    const int*   ei     = (const int*)  d_in[1];   // edge_index [2][E]
    const float* ea     = (const float*)d_in[2];   // edge_attr [E][3]
    const float* lin_w  = (const float*)d_in[3];   // [512][512]
    const float* lin_b  = (const float*)d_in[4];   // [512]
    const float* conf_w = (const float*)d_in[5];   // [3]
    const float* conf_b = (const float*)d_in[6];   // [1]
    float* out = (float*)d_out;

    int N = in_sizes[0] / NDIM;   // 50000
    int E = in_sizes[2] / 3;      // 800000

    // ---- workspace layout (256B aligned slabs) ----
    char* p = (char*)d_ws;
    auto alloc = [&](size_t bytes) {
        char* q = p;
        p += (bytes + 255) & ~(size_t)255;
        return q;
    };
    ushort* aggh       = (ushort*)alloc((size_t)N * NDIM * sizeof(ushort)); // 51.2 MB
    ushort* wh         = (ushort*)alloc((size_t)NDIM * NDIM * sizeof(ushort));
    int*   deg_row     = (int*)  alloc((size_t)N * sizeof(int));            // zeroed pair
    int*   fill_cnt    = (int*)  alloc((size_t)N * sizeof(int));            // zeroed pair

    // d_out (102.4 MB) double-duty: [0, 51.2M) = xh (bf16 x); [51.2M, 76.8M) = rn buckets
    // (NOT zeroed -- agg masks unwritten tail slots in-register). Both fully consumed by
    // agg_kernel, which completes (stream order) before mfma_gemm writes the fp32 output.
    ushort* xh = (ushort*)d_out;
    int2*   rn = (int2*)((char*)d_out + (size_t)N * NDIM * sizeof(ushort));

    size_t zero_cnt_bytes = (size_t)((char*)(fill_cnt + N) - (char*)deg_row);
    (void)hipMemsetAsync(deg_row, 0, zero_cnt_bytes, stream);   // 400 KB only

    int gE = (E + 255) / 256;
    int x4 = (N * NDIM) / 4, w4 = (NDIM * NDIM) / 4;
    int gX = (x4 + 255) / 256, gW = (w4 + 255) / 256;
    prep_kernel  <<<gX + gW + 2 * gE, 256, 0, stream>>>(
        x, xh, lin_w, wh, ei, ea, conf_w, conf_b,
        deg_row, fill_cnt, rn, x4, w4, E, gX, gW, gE);
    agg_kernel   <<<(N + 3) / 4, 256, 0, stream>>>(xh, rn, fill_cnt, deg_row, aggh, N);
    int Mb = (N + 127) >> 7;
    mfma_gemm    <<<Mb * 4, 256, 0, stream>>>(aggh, wh, lin_b, out, N);
}